// Round 19
// baseline (446.608 us; speedup 1.0000x reference)
//
#include <hip/hip_runtime.h>

#define N_NODES 65536
#define N_EDGES 1048576
#define DIM 64
#define M_POOL (N_NODES / DIM)  // 1024
#define NCB 1024                // buckets = pool windows (col>>6)
#define SEGCAP 1280             // per-window region cap (mean 1024 + 8 sigma)
#define P3CHUNK 4096            // edges per p3 block (16/thread @ 256 thr)
#define P3BLOCKS (N_EDGES / P3CHUNK)   // 256
#define GEMM_ROWS 64
#define GEMM_BLOCKS (N_NODES / GEMM_ROWS)      // 1024
#define FUSED_BLOCKS (GEMM_BLOCKS + P3BLOCKS)  // 1280, 4:1 interleave
#define CURPAD 16               // cursor padding: 1 counter per 64B line
#define APAD 68                 // acc row stride (floats) to spread banks

typedef unsigned int u32;
typedef unsigned short u16;

__device__ __forceinline__ float bf2f(u32 hi16) {
    return __uint_as_float(hi16 << 16);
}
__device__ __forceinline__ u32 f2bf(float f) {  // RNE
    u32 u = __float_as_uint(f);
    return (u + 0x7fffu + ((u >> 16) & 1u)) >> 16;
}

// ---------------- zero the padded window cursors ----------------

__global__ __launch_bounds__(256) void zero_cursor(int* __restrict__ cursor) {
    int i = blockIdx.x * 256 + threadIdx.x;
    if (i < NCB * CURPAD) cursor[i] = 0;
}

// ---------------- fused: layer-1 GEMM (4x4 reg tile) || window multisplit ---
// 1280 blocks x 256 thr, 4:1. b%5==4 -> p3 chunk b/5 (4096 edges, 16/thread,
// direct global scatter into fixed window regions); else gemm tile.

__global__ __launch_bounds__(256) void fused_gemm_p3(const float* __restrict__ x,
                                                     const float* __restrict__ W,
                                                     u16* __restrict__ hb,
                                                     const int* __restrict__ col,
                                                     const int* __restrict__ row,
                                                     const float* __restrict__ ew,
                                                     int* __restrict__ cursor,
                                                     int2* __restrict__ csr_tmp) {
    __shared__ __align__(16) char sm[33808];
    const int t = threadIdx.x;
    const int b = blockIdx.x;

    if ((b % 5) == 4) {
        // ---- p3 block: window multisplit of chunk b/5, direct writes ----
        int* h2       = (int*)sm;                 // 4096 B (1024 counters)
        int* base_blk = (int*)(sm + 4096);        // 4096 B
        const int e0 = (b / 5) * P3CHUNK + t * 16;

#pragma unroll
        for (int k = 0; k < 4; ++k) h2[t * 4 + k] = 0;
        __syncthreads();

        int cc[16], rr[16];
        float wv[16];
#pragma unroll
        for (int jj = 0; jj < 4; ++jj) {
            const int4 c4 = *(const int4*)&col[e0 + jj * 4];
            const int4 r4 = *(const int4*)&row[e0 + jj * 4];
            const float4 w4 = *(const float4*)&ew[e0 + jj * 4];
            cc[jj * 4 + 0] = c4.x; cc[jj * 4 + 1] = c4.y;
            cc[jj * 4 + 2] = c4.z; cc[jj * 4 + 3] = c4.w;
            rr[jj * 4 + 0] = r4.x; rr[jj * 4 + 1] = r4.y;
            rr[jj * 4 + 2] = r4.z; rr[jj * 4 + 3] = r4.w;
            wv[jj * 4 + 0] = w4.x; wv[jj * 4 + 1] = w4.y;
            wv[jj * 4 + 2] = w4.z; wv[jj * 4 + 3] = w4.w;
        }
#pragma unroll
        for (int j = 0; j < 16; ++j) atomicAdd(&h2[cc[j] >> 6], 1);
        __syncthreads();

        // reserve global ranges per window (line-padded cursor), reset h2
#pragma unroll
        for (int k = 0; k < 4; ++k) {
            const int c = t * 4 + k;
            const int myc = h2[c];
            base_blk[c] = myc ? atomicAdd(&cursor[c * CURPAD], myc) : 0;
            h2[c] = 0;
        }
        __syncthreads();

#pragma unroll
        for (int j = 0; j < 16; ++j) {
            const int c = cc[j] >> 6;
            const int r = atomicAdd(&h2[c], 1);
            const int bp = base_blk[c] + r;
            if (bp < SEGCAP)
                csr_tmp[c * SEGCAP + bp] =
                    make_int2((rr[j] << 6) | (cc[j] & 63), __float_as_int(wv[j]));
        }
    } else {
        // ---- gemm block: 64 rows x 64 cols, 4x4 register tile per thread ----
        float* Ws  = (float*)sm;                  // 16384 B: [64][64] k-major
        float* XsT = (float*)(sm + 16384);        // 17408 B: [64 k][68] (padded)
        const int row0 = (b - b / 5) * GEMM_ROWS;
        for (int i = t; i < DIM * DIM; i += 256) Ws[i] = W[i];
        for (int i = t; i < GEMM_ROWS * DIM; i += 256) {
            const int r = i >> 6;
            const int k = i & 63;
            XsT[k * 68 + r] = x[(size_t)(row0 + r) * DIM + k];
        }
        __syncthreads();

        const int tr = t >> 4;
        const int tc = t & 15;
        float4 a0 = {0.f, 0.f, 0.f, 0.f};
        float4 a1 = a0, a2 = a0, a3 = a0;
#pragma unroll
        for (int k = 0; k < DIM; ++k) {
            const float4 xv = *(const float4*)&XsT[k * 68 + tr * 4];
            const float4 wv = *(const float4*)&Ws[k * DIM + tc * 4];
            a0.x += xv.x * wv.x; a0.y += xv.x * wv.y;
            a0.z += xv.x * wv.z; a0.w += xv.x * wv.w;
            a1.x += xv.y * wv.x; a1.y += xv.y * wv.y;
            a1.z += xv.y * wv.z; a1.w += xv.y * wv.w;
            a2.x += xv.z * wv.x; a2.y += xv.z * wv.y;
            a2.z += xv.z * wv.z; a2.w += xv.z * wv.w;
            a3.x += xv.w * wv.x; a3.y += xv.w * wv.y;
            a3.z += xv.w * wv.z; a3.w += xv.w * wv.w;
        }
        const size_t base = (size_t)(row0 + tr * 4) * DIM + tc * 4;
        ushort4 o;
        o.x = (u16)f2bf(a0.x); o.y = (u16)f2bf(a0.y);
        o.z = (u16)f2bf(a0.z); o.w = (u16)f2bf(a0.w);
        *(ushort4*)&hb[base] = o;
        o.x = (u16)f2bf(a1.x); o.y = (u16)f2bf(a1.y);
        o.z = (u16)f2bf(a1.z); o.w = (u16)f2bf(a1.w);
        *(ushort4*)&hb[base + DIM] = o;
        o.x = (u16)f2bf(a2.x); o.y = (u16)f2bf(a2.y);
        o.z = (u16)f2bf(a2.z); o.w = (u16)f2bf(a2.w);
        *(ushort4*)&hb[base + 2 * DIM] = o;
        o.x = (u16)f2bf(a3.x); o.y = (u16)f2bf(a3.y);
        o.z = (u16)f2bf(a3.z); o.w = (u16)f2bf(a3.w);
        *(ushort4*)&hb[base + 3 * DIM] = o;
    }
}

// ---------------- K3: per-window deg/dinv + hb premultiply ------------------

__global__ __launch_bounds__(256) void deg_dinv_premult(const int* __restrict__ cursor,
                                                        const int2* __restrict__ csrt,
                                                        float* __restrict__ dinv,
                                                        u16* __restrict__ hb) {
    __shared__ float degw[64];
    __shared__ float dvs[64];
    const int t = threadIdx.x;
    const int w = blockIdx.x;
    const int segN = min(cursor[w * CURPAD], SEGCAP);
    if (t < 64) degw[t] = 0.f;
    __syncthreads();
    for (int i = t; i < segN; i += 256) {
        const int2 a = csrt[w * SEGCAP + i];
        atomicAdd(&degw[a.x & 63], __int_as_float(a.y));
    }
    __syncthreads();
    if (t < 64) {
        dvs[t] = rsqrtf(1.0f + degw[t]);
        dinv[w * 64 + t] = dvs[t];
    }
    __syncthreads();
    for (int idx = t; idx < 512; idx += 256) {
        const int nl = idx >> 3;
        const int part = idx & 7;
        const float dv = dvs[nl];
        const size_t p = (size_t)(w * 64 + nl) * DIM + part * 8;
        uint4 v = *(const uint4*)&hb[p];
        uint4 o;
        o.x = f2bf(dv * bf2f(v.x & 0xffff)) | (f2bf(dv * bf2f(v.x >> 16)) << 16);
        o.y = f2bf(dv * bf2f(v.y & 0xffff)) | (f2bf(dv * bf2f(v.y >> 16)) << 16);
        o.z = f2bf(dv * bf2f(v.z & 0xffff)) | (f2bf(dv * bf2f(v.z >> 16)) << 16);
        o.w = f2bf(dv * bf2f(v.w & 0xffff)) | (f2bf(dv * bf2f(v.w >> 16)) << 16);
        *(uint4*)&hb[p] = o;
    }
}

// ---------------- K4: agg1 per window, unsorted bucket, LDS accumulators ----
// acc[fine][dim] (+APAD stride). h1p = bf16(dv*(acc + dv*hb2[self] + bias)).

__global__ __launch_bounds__(256) void agg1_win(const int* __restrict__ cursor,
                                                const int2* __restrict__ csrt,
                                                const u16* __restrict__ hb2,
                                                const float* __restrict__ bias,
                                                const float* __restrict__ dinv,
                                                u16* __restrict__ ob) {
    __shared__ float acc[64 * APAD];    // 17408 B
    __shared__ float dvs[64];
    __shared__ float bsh[64];
    const int t = threadIdx.x;
    const int w = blockIdx.x;
    const int segN = min(cursor[w * CURPAD], SEGCAP);
    for (int i = t; i < 64 * APAD; i += 256) acc[i] = 0.f;
    if (t < 64) { dvs[t] = dinv[w * 64 + t]; bsh[t] = bias[t]; }
    __syncthreads();

    const int eoff = t >> 3;   // 0..31
    const int q = t & 7;       // dim octet
    const int base = w * SEGCAP;
    for (int i = 0; i < segN; i += 128) {
        const int e0 = i + eoff;
        const int e1 = i + 32 + eoff;
        const int e2 = i + 64 + eoff;
        const int e3 = i + 96 + eoff;
        const int2 a0 = (e0 < segN) ? csrt[base + e0] : make_int2(0, 0);
        const int2 a1 = (e1 < segN) ? csrt[base + e1] : make_int2(0, 0);
        const int2 a2 = (e2 < segN) ? csrt[base + e2] : make_int2(0, 0);
        const int2 a3 = (e3 < segN) ? csrt[base + e3] : make_int2(0, 0);
        const int f0 = a0.x & 63, f1 = a1.x & 63, f2 = a2.x & 63, f3 = a3.x & 63;
        const float w0 = (e0 < segN) ? __int_as_float(a0.y) * dvs[f0] : 0.f;
        const float w1 = (e1 < segN) ? __int_as_float(a1.y) * dvs[f1] : 0.f;
        const float w2 = (e2 < segN) ? __int_as_float(a2.y) * dvs[f2] : 0.f;
        const float w3 = (e3 < segN) ? __int_as_float(a3.y) * dvs[f3] : 0.f;
        const uint4 B0 = *(const uint4*)&hb2[(size_t)(a0.x >> 6) * DIM + q * 8];
        const uint4 B1 = *(const uint4*)&hb2[(size_t)(a1.x >> 6) * DIM + q * 8];
        const uint4 B2 = *(const uint4*)&hb2[(size_t)(a2.x >> 6) * DIM + q * 8];
        const uint4 B3 = *(const uint4*)&hb2[(size_t)(a3.x >> 6) * DIM + q * 8];
        float* p0 = &acc[f0 * APAD + q * 8];
        float* p1 = &acc[f1 * APAD + q * 8];
        float* p2 = &acc[f2 * APAD + q * 8];
        float* p3 = &acc[f3 * APAD + q * 8];
        atomicAdd(&p0[0], w0 * bf2f(B0.x & 0xffff));
        atomicAdd(&p0[1], w0 * bf2f(B0.x >> 16));
        atomicAdd(&p0[2], w0 * bf2f(B0.y & 0xffff));
        atomicAdd(&p0[3], w0 * bf2f(B0.y >> 16));
        atomicAdd(&p0[4], w0 * bf2f(B0.z & 0xffff));
        atomicAdd(&p0[5], w0 * bf2f(B0.z >> 16));
        atomicAdd(&p0[6], w0 * bf2f(B0.w & 0xffff));
        atomicAdd(&p0[7], w0 * bf2f(B0.w >> 16));
        atomicAdd(&p1[0], w1 * bf2f(B1.x & 0xffff));
        atomicAdd(&p1[1], w1 * bf2f(B1.x >> 16));
        atomicAdd(&p1[2], w1 * bf2f(B1.y & 0xffff));
        atomicAdd(&p1[3], w1 * bf2f(B1.y >> 16));
        atomicAdd(&p1[4], w1 * bf2f(B1.z & 0xffff));
        atomicAdd(&p1[5], w1 * bf2f(B1.z >> 16));
        atomicAdd(&p1[6], w1 * bf2f(B1.w & 0xffff));
        atomicAdd(&p1[7], w1 * bf2f(B1.w >> 16));
        atomicAdd(&p2[0], w2 * bf2f(B2.x & 0xffff));
        atomicAdd(&p2[1], w2 * bf2f(B2.x >> 16));
        atomicAdd(&p2[2], w2 * bf2f(B2.y & 0xffff));
        atomicAdd(&p2[3], w2 * bf2f(B2.y >> 16));
        atomicAdd(&p2[4], w2 * bf2f(B2.z & 0xffff));
        atomicAdd(&p2[5], w2 * bf2f(B2.z >> 16));
        atomicAdd(&p2[6], w2 * bf2f(B2.w & 0xffff));
        atomicAdd(&p2[7], w2 * bf2f(B2.w >> 16));
        atomicAdd(&p3[0], w3 * bf2f(B3.x & 0xffff));
        atomicAdd(&p3[1], w3 * bf2f(B3.x >> 16));
        atomicAdd(&p3[2], w3 * bf2f(B3.y & 0xffff));
        atomicAdd(&p3[3], w3 * bf2f(B3.y >> 16));
        atomicAdd(&p3[4], w3 * bf2f(B3.z & 0xffff));
        atomicAdd(&p3[5], w3 * bf2f(B3.z >> 16));
        atomicAdd(&p3[6], w3 * bf2f(B3.w & 0xffff));
        atomicAdd(&p3[7], w3 * bf2f(B3.w >> 16));
    }
    __syncthreads();

    for (int idx = t; idx < 512; idx += 256) {
        const int nl = idx >> 3;
        const int part = idx & 7;
        const float dv = dvs[nl];
        const uint4 S = *(const uint4*)&hb2[(size_t)(w * 64 + nl) * DIM + part * 8];
        const float* ap = &acc[nl * APAD + part * 8];
        float r[8];
        r[0] = dv * (ap[0] + dv * bf2f(S.x & 0xffff) + bsh[part * 8 + 0]);
        r[1] = dv * (ap[1] + dv * bf2f(S.x >> 16)    + bsh[part * 8 + 1]);
        r[2] = dv * (ap[2] + dv * bf2f(S.y & 0xffff) + bsh[part * 8 + 2]);
        r[3] = dv * (ap[3] + dv * bf2f(S.y >> 16)    + bsh[part * 8 + 3]);
        r[4] = dv * (ap[4] + dv * bf2f(S.z & 0xffff) + bsh[part * 8 + 4]);
        r[5] = dv * (ap[5] + dv * bf2f(S.z >> 16)    + bsh[part * 8 + 5]);
        r[6] = dv * (ap[6] + dv * bf2f(S.w & 0xffff) + bsh[part * 8 + 6]);
        r[7] = dv * (ap[7] + dv * bf2f(S.w >> 16)    + bsh[part * 8 + 7]);
        uint4 o;
        o.x = f2bf(r[0]) | (f2bf(r[1]) << 16);
        o.y = f2bf(r[2]) | (f2bf(r[3]) << 16);
        o.z = f2bf(r[4]) | (f2bf(r[5]) << 16);
        o.w = f2bf(r[6]) | (f2bf(r[7]) << 16);
        *(uint4*)&ob[(size_t)(w * 64 + nl) * DIM + part * 8] = o;
    }
}

// ---------------- K5: layer-2 aggregate + pool + W2 GEMM (flat window) ------

__global__ __launch_bounds__(512) void agg2_pool_gemm(const int* __restrict__ cursor,
                                                      const int2* __restrict__ csrt,
                                                      const u16* __restrict__ hb,
                                                      const float* __restrict__ dinv,
                                                      const float* __restrict__ W2,
                                                      const float* __restrict__ b2,
                                                      float* __restrict__ out) {
    __shared__ float Ws[DIM * DIM];
    __shared__ float wacc[8][DIM];
    __shared__ float pooled[DIM];
    __shared__ float dvs[64];
    const int t = threadIdx.x;
    const int m = blockIdx.x;

    for (int i = t; i < DIM * DIM; i += 512) Ws[i] = W2[i];
    if (t < 64) dvs[t] = dinv[m * 64 + t];

    const int wave = t >> 6;
    const int lane = t & 63;
    const int g = lane >> 3;
    const int q = lane & 7;

    const int base = m * SEGCAP;
    const int segN = min(cursor[m * CURPAD], SEGCAP);
    __syncthreads();

    float acc[8];
#pragma unroll
    for (int k = 0; k < 8; ++k) acc[k] = 0.f;

    for (int i = wave * 32; i < segN; i += 256) {
        const int e0 = i + g;
        const int e1 = i + 8 + g;
        const int e2 = i + 16 + g;
        const int e3 = i + 24 + g;
        const int2 a0 = (e0 < segN) ? csrt[base + e0] : make_int2(0, 0);
        const int2 a1 = (e1 < segN) ? csrt[base + e1] : make_int2(0, 0);
        const int2 a2 = (e2 < segN) ? csrt[base + e2] : make_int2(0, 0);
        const int2 a3 = (e3 < segN) ? csrt[base + e3] : make_int2(0, 0);
        const float w0 = (e0 < segN) ? __int_as_float(a0.y) * dvs[a0.x & 63] : 0.f;
        const float w1 = (e1 < segN) ? __int_as_float(a1.y) * dvs[a1.x & 63] : 0.f;
        const float w2 = (e2 < segN) ? __int_as_float(a2.y) * dvs[a2.x & 63] : 0.f;
        const float w3 = (e3 < segN) ? __int_as_float(a3.y) * dvs[a3.x & 63] : 0.f;
        const uint4 B0 = *(const uint4*)&hb[(size_t)(a0.x >> 6) * DIM + q * 8];
        const uint4 B1 = *(const uint4*)&hb[(size_t)(a1.x >> 6) * DIM + q * 8];
        const uint4 B2 = *(const uint4*)&hb[(size_t)(a2.x >> 6) * DIM + q * 8];
        const uint4 B3 = *(const uint4*)&hb[(size_t)(a3.x >> 6) * DIM + q * 8];
        acc[0] += w0 * bf2f(B0.x & 0xffff) + w1 * bf2f(B1.x & 0xffff)
                + w2 * bf2f(B2.x & 0xffff) + w3 * bf2f(B3.x & 0xffff);
        acc[1] += w0 * bf2f(B0.x >> 16)    + w1 * bf2f(B1.x >> 16)
                + w2 * bf2f(B2.x >> 16)    + w3 * bf2f(B3.x >> 16);
        acc[2] += w0 * bf2f(B0.y & 0xffff) + w1 * bf2f(B1.y & 0xffff)
                + w2 * bf2f(B2.y & 0xffff) + w3 * bf2f(B3.y & 0xffff);
        acc[3] += w0 * bf2f(B0.y >> 16)    + w1 * bf2f(B1.y >> 16)
                + w2 * bf2f(B2.y >> 16)    + w3 * bf2f(B3.y >> 16);
        acc[4] += w0 * bf2f(B0.z & 0xffff) + w1 * bf2f(B1.z & 0xffff)
                + w2 * bf2f(B2.z & 0xffff) + w3 * bf2f(B3.z & 0xffff);
        acc[5] += w0 * bf2f(B0.z >> 16)    + w1 * bf2f(B1.z >> 16)
                + w2 * bf2f(B2.z >> 16)    + w3 * bf2f(B3.z >> 16);
        acc[6] += w0 * bf2f(B0.w & 0xffff) + w1 * bf2f(B1.w & 0xffff)
                + w2 * bf2f(B2.w & 0xffff) + w3 * bf2f(B3.w & 0xffff);
        acc[7] += w0 * bf2f(B0.w >> 16)    + w1 * bf2f(B1.w >> 16)
                + w2 * bf2f(B2.w >> 16)    + w3 * bf2f(B3.w >> 16);
    }

    // self terms: wave handles nodes m*64 + wave*8 + g (each exactly once)
    {
        const int nl = wave * 8 + g;
        const float dv = dvs[nl];
        const uint4 S = *(const uint4*)&hb[(size_t)(m * 64 + nl) * DIM + q * 8];
        acc[0] += dv * bf2f(S.x & 0xffff);
        acc[1] += dv * bf2f(S.x >> 16);
        acc[2] += dv * bf2f(S.y & 0xffff);
        acc[3] += dv * bf2f(S.y >> 16);
        acc[4] += dv * bf2f(S.z & 0xffff);
        acc[5] += dv * bf2f(S.z >> 16);
        acc[6] += dv * bf2f(S.w & 0xffff);
        acc[7] += dv * bf2f(S.w >> 16);
    }

#pragma unroll
    for (int mm = 8; mm <= 32; mm <<= 1) {
#pragma unroll
        for (int k = 0; k < 8; ++k) acc[k] += __shfl_xor(acc[k], mm, 64);
    }
    if (lane < 8) {
#pragma unroll
        for (int k = 0; k < 8; ++k) wacc[wave][q * 8 + k] = acc[k];
    }
    __syncthreads();
    if (t < DIM) {
        float p = 0.f;
#pragma unroll
        for (int w = 0; w < 8; ++w) p += wacc[w][t];
        pooled[t] = p * (1.0f / DIM);
    }
    __syncthreads();
    if (t < DIM) {
        float o = b2[t];
#pragma unroll
        for (int k = 0; k < DIM; ++k) o += pooled[k] * Ws[k * DIM + t];
        out[(size_t)t * M_POOL + m] = o;
    }
}

// ---------------- launcher --------------------------------------------------

extern "C" void kernel_launch(void* const* d_in, const int* in_sizes, int n_in,
                              void* d_out, int out_size, void* d_ws, size_t ws_size,
                              hipStream_t stream) {
    const float* x  = (const float*)d_in[0];
    const int*   ei = (const int*)d_in[1];   // [2][E]
    const float* ew = (const float*)d_in[2];
    const float* W1 = (const float*)d_in[3];
    const float* b1 = (const float*)d_in[4];
    const float* W2 = (const float*)d_in[5];
    const float* b2 = (const float*)d_in[6];
    float* out = (float*)d_out;

    char* w = (char*)d_ws;
    int*   cursor = (int*)w;   w += (size_t)NCB * CURPAD * 4;        // 64 KB padded
    float* dinv   = (float*)w; w += (size_t)N_NODES * 4;             // 0.25 MB
    int2*  csrt   = (int2*)w;  w += (size_t)NCB * SEGCAP * 8;        // 10.5 MB
    u16*   hbf    = (u16*)w;   w += (size_t)N_NODES * DIM * 2;       // 8 MB
    u16*   h1bf   = (u16*)w;                                         // 8 MB

    const int* row = ei;             // edge_index[0]
    const int* col = ei + N_EDGES;   // edge_index[1]

    // build: gemm || window-multisplit (direct, unsorted buckets)
    zero_cursor<<<NCB * CURPAD / 256, 256, 0, stream>>>(cursor);
    fused_gemm_p3<<<FUSED_BLOCKS, 256, 0, stream>>>(x, W1, hbf, col, row, ew,
                                                    cursor, csrt);
    // per-window deg/dinv + premultiply hb
    deg_dinv_premult<<<NCB, 256, 0, stream>>>(cursor, csrt, dinv, hbf);

    // layer 1 aggregate (unsorted window buckets, LDS node accumulators)
    agg1_win<<<NCB, 256, 0, stream>>>(cursor, csrt, hbf, b1, dinv, h1bf);

    // layer 2 + pool + W2-GEMM fused per window (flat window range)
    agg2_pool_gemm<<<NCB, 512, 0, stream>>>(cursor, csrt, h1bf, dinv, W2, b2, out);
}

// Round 20
// 109.392 us; speedup vs baseline: 4.0826x; 4.0826x over previous
//
#include <hip/hip_runtime.h>

#define N_NODES 65536
#define N_EDGES 1048576
#define DIM 64
#define M_POOL (N_NODES / DIM)  // 1024
#define NCOARSE 256             // coarse buckets (col>>8), 256 nodes each
#define SEGCAP 5120             // fixed region per coarse bucket (mean 4096 + 16 sigma)
#define P3CHUNK 4096            // edges per p3 block (16/thread @ 256 thr)
#define P3BLOCKS (N_EDGES / P3CHUNK)   // 256
#define GEMM_ROWS 64
#define GEMM_BLOCKS (N_NODES / GEMM_ROWS)      // 1024
#define FUSED_BLOCKS (GEMM_BLOCKS + P3BLOCKS)  // 1280, 4:1 interleave
#define CURPAD 16               // cursor padding: 1 counter per 64B line

typedef unsigned int u32;
typedef unsigned short u16;

__device__ __forceinline__ float bf2f(u32 hi16) {
    return __uint_as_float(hi16 << 16);
}
__device__ __forceinline__ u32 f2bf(float f) {  // RNE
    u32 u = __float_as_uint(f);
    return (u + 0x7fffu + ((u >> 16) & 1u)) >> 16;
}

// inclusive scan of arr[256] by threads t<256 (4 full waves), 2 syncs.
__device__ __forceinline__ void scan256_wave(int* arr, int* wsum, int t) {
    int s = 0;
    if (t < 256) {
        s = arr[t];
        const int lane = t & 63;
#pragma unroll
        for (int o = 1; o < 64; o <<= 1) {
            const int u = __shfl_up(s, o, 64);
            if (lane >= o) s += u;
        }
        if (lane == 63) wsum[t >> 6] = s;
    }
    __syncthreads();
    if (t < 256) {
        const int w = t >> 6;
        int add = 0;
#pragma unroll
        for (int k = 0; k < 4; ++k)
            if (k < w) add += wsum[k];
        arr[t] = s + add;
    }
    __syncthreads();
}

// ---------------- zero the padded coarse cursors ----------------

__global__ __launch_bounds__(256) void zero_cursor(int* __restrict__ cursor) {
    for (int i = threadIdx.x; i < NCOARSE * CURPAD; i += 256) cursor[i] = 0;
}

// ---------------- fused: layer-1 GEMM (4x4 reg tile) || coarse multisplit ---
// 1280 blocks x 256 thr, 4:1. b%5==4 -> p3 chunk b/5 (4096 edges, 16/thread,
// direct global scatter, NO block-local scan); else gemm tile (b-b/5)*64 rows.

__global__ __launch_bounds__(256) void fused_gemm_p3(const float* __restrict__ x,
                                                     const float* __restrict__ W,
                                                     u16* __restrict__ hb,
                                                     const int* __restrict__ col,
                                                     const int* __restrict__ row,
                                                     const float* __restrict__ ew,
                                                     int* __restrict__ cursor,
                                                     int2* __restrict__ csr_tmp) {
    __shared__ __align__(16) char sm[33808];
    const int t = threadIdx.x;
    const int b = blockIdx.x;

    if ((b % 5) == 4) {
        // ---- p3 block: coarse multisplit of chunk b/5, direct writes ----
        int* h2       = (int*)sm;                 // 1024 B
        int* base_blk = (int*)(sm + 1024);        // 1024 B
        const int e0 = (b / 5) * P3CHUNK + t * 16;

        h2[t] = 0;
        __syncthreads();

        int cc[16], rr[16];
        float wv[16];
#pragma unroll
        for (int jj = 0; jj < 4; ++jj) {
            const int4 c4 = *(const int4*)&col[e0 + jj * 4];
            const int4 r4 = *(const int4*)&row[e0 + jj * 4];
            const float4 w4 = *(const float4*)&ew[e0 + jj * 4];
            cc[jj * 4 + 0] = c4.x; cc[jj * 4 + 1] = c4.y;
            cc[jj * 4 + 2] = c4.z; cc[jj * 4 + 3] = c4.w;
            rr[jj * 4 + 0] = r4.x; rr[jj * 4 + 1] = r4.y;
            rr[jj * 4 + 2] = r4.z; rr[jj * 4 + 3] = r4.w;
            wv[jj * 4 + 0] = w4.x; wv[jj * 4 + 1] = w4.y;
            wv[jj * 4 + 2] = w4.z; wv[jj * 4 + 3] = w4.w;
        }
#pragma unroll
        for (int j = 0; j < 16; ++j) atomicAdd(&h2[cc[j] >> 8], 1);
        __syncthreads();

        // reserve global ranges per bucket (line-padded cursor), reset h2
        {
            const int myc = h2[t];
            base_blk[t] = myc ? atomicAdd(&cursor[t * CURPAD], myc) : 0;
            h2[t] = 0;
        }
        __syncthreads();

#pragma unroll
        for (int j = 0; j < 16; ++j) {
            const int c = cc[j] >> 8;
            const int r = atomicAdd(&h2[c], 1);
            const int bp = base_blk[c] + r;
            if (bp < SEGCAP)
                csr_tmp[c * SEGCAP + bp] =
                    make_int2((rr[j] << 8) | (cc[j] & 255), __float_as_int(wv[j]));
        }
    } else {
        // ---- gemm block: 64 rows x 64 cols, 4x4 register tile per thread ----
        float* Ws  = (float*)sm;                  // 16384 B: [64][64] k-major
        float* XsT = (float*)(sm + 16384);        // 17408 B: [64 k][68] (padded)
        const int row0 = (b - b / 5) * GEMM_ROWS;
        for (int i = t; i < DIM * DIM; i += 256) Ws[i] = W[i];
        for (int i = t; i < GEMM_ROWS * DIM; i += 256) {
            const int r = i >> 6;
            const int k = i & 63;
            XsT[k * 68 + r] = x[(size_t)(row0 + r) * DIM + k];
        }
        __syncthreads();

        const int tr = t >> 4;    // 0..15 -> rows tr*4..+3
        const int tc = t & 15;    // 0..15 -> cols tc*4..+3
        float4 a0 = {0.f, 0.f, 0.f, 0.f};
        float4 a1 = a0, a2 = a0, a3 = a0;
#pragma unroll
        for (int k = 0; k < DIM; ++k) {
            const float4 xv = *(const float4*)&XsT[k * 68 + tr * 4];
            const float4 wv = *(const float4*)&Ws[k * DIM + tc * 4];
            a0.x += xv.x * wv.x; a0.y += xv.x * wv.y;
            a0.z += xv.x * wv.z; a0.w += xv.x * wv.w;
            a1.x += xv.y * wv.x; a1.y += xv.y * wv.y;
            a1.z += xv.y * wv.z; a1.w += xv.y * wv.w;
            a2.x += xv.z * wv.x; a2.y += xv.z * wv.y;
            a2.z += xv.z * wv.z; a2.w += xv.z * wv.w;
            a3.x += xv.w * wv.x; a3.y += xv.w * wv.y;
            a3.z += xv.w * wv.z; a3.w += xv.w * wv.w;
        }
        const size_t base = (size_t)(row0 + tr * 4) * DIM + tc * 4;
        ushort4 o;
        o.x = (u16)f2bf(a0.x); o.y = (u16)f2bf(a0.y);
        o.z = (u16)f2bf(a0.z); o.w = (u16)f2bf(a0.w);
        *(ushort4*)&hb[base] = o;
        o.x = (u16)f2bf(a1.x); o.y = (u16)f2bf(a1.y);
        o.z = (u16)f2bf(a1.z); o.w = (u16)f2bf(a1.w);
        *(ushort4*)&hb[base + DIM] = o;
        o.x = (u16)f2bf(a2.x); o.y = (u16)f2bf(a2.y);
        o.z = (u16)f2bf(a2.z); o.w = (u16)f2bf(a2.w);
        *(ushort4*)&hb[base + 2 * DIM] = o;
        o.x = (u16)f2bf(a3.x); o.y = (u16)f2bf(a3.y);
        o.z = (u16)f2bf(a3.z); o.w = (u16)f2bf(a3.w);
        *(ushort4*)&hb[base + 3 * DIM] = o;
    }
}

// ---------------- P4: fine sort + dinv + rowptr + premult; 4B csr out -------

__global__ __launch_bounds__(512) void p4_fine(const int* __restrict__ cursor,
                                               const int2* __restrict__ csr_tmp,
                                               u32* __restrict__ csr,
                                               int* __restrict__ rowptr,
                                               float* __restrict__ dinv,
                                               u16* __restrict__ hb) {
    __shared__ int2 A[SEGCAP];          // 40 KB
    __shared__ u32 Bu[SEGCAP];          // 20 KB
    __shared__ int fh[NCOARSE];
    __shared__ int off2[NCOARSE];
    __shared__ int cbase[NCOARSE];
    __shared__ float degw[NCOARSE];
    __shared__ float dvs[NCOARSE];
    __shared__ int wsum[4];
    const int t = threadIdx.x;
    const int c = blockIdx.x;
    const int segN = min(cursor[c * CURPAD], SEGCAP);

    // inclusive scan of clamped cursors -> output base for bucket c
    if (t < NCOARSE) cbase[t] = min(cursor[t * CURPAD], SEGCAP);
    __syncthreads();
    scan256_wave(cbase, wsum, t);
    const int seg0_out = cbase[c] - segN;

    for (int i = t; i < segN; i += 512) A[i] = csr_tmp[c * SEGCAP + i];
    if (t < NCOARSE) { fh[t] = 0; degw[t] = 0.f; }
    __syncthreads();

    for (int i = t; i < segN; i += 512) {
        const int f = A[i].x & 255;
        atomicAdd(&fh[f], 1);
        atomicAdd(&degw[f], __int_as_float(A[i].y));
    }
    __syncthreads();

    if (t < NCOARSE) off2[t] = fh[t];
    __syncthreads();
    scan256_wave(off2, wsum, t);
    if (t < NCOARSE) {
        off2[t] -= fh[t];                         // exclusive
        const float dv = rsqrtf(1.0f + degw[t]);
        dvs[t] = dv;
        dinv[c * 256 + t] = dv;
        rowptr[c * 256 + t] = seg0_out + off2[t];
        fh[t] = 0;                                // reset for rank pass
    }
    if (c == NCOARSE - 1 && t == 0) rowptr[N_NODES] = seg0_out + segN;
    __syncthreads();

    // premultiply hb rows of this bucket's 256 nodes by their dinv
    for (int idx = t; idx < 256 * 8; idx += 512) {
        const int nl = idx >> 3;
        const int part = idx & 7;
        const float dv = dvs[nl];
        const size_t p = (size_t)(c * 256 + nl) * DIM + part * 8;
        uint4 v = *(const uint4*)&hb[p];
        uint4 o;
        o.x = f2bf(dv * bf2f(v.x & 0xffff)) | (f2bf(dv * bf2f(v.x >> 16)) << 16);
        o.y = f2bf(dv * bf2f(v.y & 0xffff)) | (f2bf(dv * bf2f(v.y >> 16)) << 16);
        o.z = f2bf(dv * bf2f(v.z & 0xffff)) | (f2bf(dv * bf2f(v.z >> 16)) << 16);
        o.w = f2bf(dv * bf2f(v.w & 0xffff)) | (f2bf(dv * bf2f(v.w >> 16)) << 16);
        *(uint4*)&hb[p] = o;
    }

    for (int i = t; i < segN; i += 512) {
        const int f = A[i].x & 255;
        const int r = atomicAdd(&fh[f], 1);
        const float w = __int_as_float(A[i].y) * dvs[f];
        Bu[off2[f] + r] = (f2bf(w) << 16) | ((u32)(A[i].x >> 8) & 0xffffu);
    }
    __syncthreads();
    for (int i = t; i < segN; i += 512)           // fully coalesced
        csr[seg0_out + i] = Bu[i];
}

// ---------------- aggregate layer 1 (4B csr; premult tables) ----------------
// h1p = bf16( dv * ( sum(w_e * hb2[src_e]) + dv*hb2[node] + bias ) )

__global__ __launch_bounds__(256) void aggregate_l1(const int* __restrict__ rowptr,
                                                    const u32* __restrict__ csr,
                                                    const u16* __restrict__ hb2,
                                                    const float* __restrict__ dinv,
                                                    const float* __restrict__ bias,
                                                    u16* __restrict__ ob) {
    const int lane = threadIdx.x & 63;
    const int node = (blockIdx.x * 256 + threadIdx.x) >> 6;
    const int g = lane >> 3;
    const int q = lane & 7;
    const int start = rowptr[node];
    const int end = rowptr[node + 1];
    const float dv = dinv[node];

    float acc[8];
#pragma unroll
    for (int k = 0; k < 8; ++k) acc[k] = 0.f;

    for (int i = start; i < end; i += 16) {
        const int i0 = i + g;
        const int i1 = i + 8 + g;
        const u32 v0 = (i0 < end) ? csr[i0] : 0;
        const u32 v1 = (i1 < end) ? csr[i1] : 0;
        const float w0 = bf2f(v0 >> 16);
        const float w1 = bf2f(v1 >> 16);
        const uint4 B0 = *(const uint4*)&hb2[(size_t)(v0 & 0xffffu) * DIM + q * 8];
        const uint4 B1 = *(const uint4*)&hb2[(size_t)(v1 & 0xffffu) * DIM + q * 8];
        acc[0] += w0 * bf2f(B0.x & 0xffff) + w1 * bf2f(B1.x & 0xffff);
        acc[1] += w0 * bf2f(B0.x >> 16)    + w1 * bf2f(B1.x >> 16);
        acc[2] += w0 * bf2f(B0.y & 0xffff) + w1 * bf2f(B1.y & 0xffff);
        acc[3] += w0 * bf2f(B0.y >> 16)    + w1 * bf2f(B1.y >> 16);
        acc[4] += w0 * bf2f(B0.z & 0xffff) + w1 * bf2f(B1.z & 0xffff);
        acc[5] += w0 * bf2f(B0.z >> 16)    + w1 * bf2f(B1.z >> 16);
        acc[6] += w0 * bf2f(B0.w & 0xffff) + w1 * bf2f(B1.w & 0xffff);
        acc[7] += w0 * bf2f(B0.w >> 16)    + w1 * bf2f(B1.w >> 16);
    }
#pragma unroll
    for (int m = 8; m <= 32; m <<= 1) {
#pragma unroll
        for (int k = 0; k < 8; ++k) acc[k] += __shfl_xor(acc[k], m, 64);
    }
    if (lane < 8) {
        const uint4 S = *(const uint4*)&hb2[(size_t)node * DIM + q * 8];
        float r[8];
        r[0] = dv * (acc[0] + dv * bf2f(S.x & 0xffff) + bias[q * 8 + 0]);
        r[1] = dv * (acc[1] + dv * bf2f(S.x >> 16)    + bias[q * 8 + 1]);
        r[2] = dv * (acc[2] + dv * bf2f(S.y & 0xffff) + bias[q * 8 + 2]);
        r[3] = dv * (acc[3] + dv * bf2f(S.y >> 16)    + bias[q * 8 + 3]);
        r[4] = dv * (acc[4] + dv * bf2f(S.z & 0xffff) + bias[q * 8 + 4]);
        r[5] = dv * (acc[5] + dv * bf2f(S.z >> 16)    + bias[q * 8 + 5]);
        r[6] = dv * (acc[6] + dv * bf2f(S.w & 0xffff) + bias[q * 8 + 6]);
        r[7] = dv * (acc[7] + dv * bf2f(S.w >> 16)    + bias[q * 8 + 7]);
        uint4 o;
        o.x = f2bf(r[0]) | (f2bf(r[1]) << 16);
        o.y = f2bf(r[2]) | (f2bf(r[3]) << 16);
        o.z = f2bf(r[4]) | (f2bf(r[5]) << 16);
        o.w = f2bf(r[6]) | (f2bf(r[7]) << 16);
        *(uint4*)&ob[(size_t)node * DIM + q * 8] = o;
    }
}

// ---------------- fused: layer-2 aggregate + pool + W2 GEMM (flat range) ----

__global__ __launch_bounds__(512) void agg2_pool_gemm(const int* __restrict__ rowptr,
                                                      const u32* __restrict__ csr,
                                                      const u16* __restrict__ hb,
                                                      const float* __restrict__ dinv,
                                                      const float* __restrict__ W2,
                                                      const float* __restrict__ b2,
                                                      float* __restrict__ out) {
    __shared__ float Ws[DIM * DIM];
    __shared__ float wacc[8][DIM];
    __shared__ float pooled[DIM];
    __shared__ float dvs[64];
    const int t = threadIdx.x;
    const int m = blockIdx.x;

    for (int i = t; i < DIM * DIM; i += 512) Ws[i] = W2[i];
    if (t < 64) dvs[t] = dinv[m * 64 + t];

    const int wave = t >> 6;
    const int lane = t & 63;
    const int g = lane >> 3;
    const int q = lane & 7;

    const int start = rowptr[m * 64];
    const int end = rowptr[m * 64 + 64];
    __syncthreads();

    float acc[8];
#pragma unroll
    for (int k = 0; k < 8; ++k) acc[k] = 0.f;

    for (int i = start + wave * 32; i < end; i += 256) {
        const int i0 = i + g;
        const int i1 = i + 8 + g;
        const int i2 = i + 16 + g;
        const int i3 = i + 24 + g;
        const u32 v0 = (i0 < end) ? csr[i0] : 0;
        const u32 v1 = (i1 < end) ? csr[i1] : 0;
        const u32 v2 = (i2 < end) ? csr[i2] : 0;
        const u32 v3 = (i3 < end) ? csr[i3] : 0;
        const float w0 = bf2f(v0 >> 16);
        const float w1 = bf2f(v1 >> 16);
        const float w2 = bf2f(v2 >> 16);
        const float w3 = bf2f(v3 >> 16);
        const uint4 B0 = *(const uint4*)&hb[(size_t)(v0 & 0xffffu) * DIM + q * 8];
        const uint4 B1 = *(const uint4*)&hb[(size_t)(v1 & 0xffffu) * DIM + q * 8];
        const uint4 B2 = *(const uint4*)&hb[(size_t)(v2 & 0xffffu) * DIM + q * 8];
        const uint4 B3 = *(const uint4*)&hb[(size_t)(v3 & 0xffffu) * DIM + q * 8];
        acc[0] += w0 * bf2f(B0.x & 0xffff) + w1 * bf2f(B1.x & 0xffff)
                + w2 * bf2f(B2.x & 0xffff) + w3 * bf2f(B3.x & 0xffff);
        acc[1] += w0 * bf2f(B0.x >> 16)    + w1 * bf2f(B1.x >> 16)
                + w2 * bf2f(B2.x >> 16)    + w3 * bf2f(B3.x >> 16);
        acc[2] += w0 * bf2f(B0.y & 0xffff) + w1 * bf2f(B1.y & 0xffff)
                + w2 * bf2f(B2.y & 0xffff) + w3 * bf2f(B3.y & 0xffff);
        acc[3] += w0 * bf2f(B0.y >> 16)    + w1 * bf2f(B1.y >> 16)
                + w2 * bf2f(B2.y >> 16)    + w3 * bf2f(B3.y >> 16);
        acc[4] += w0 * bf2f(B0.z & 0xffff) + w1 * bf2f(B1.z & 0xffff)
                + w2 * bf2f(B2.z & 0xffff) + w3 * bf2f(B3.z & 0xffff);
        acc[5] += w0 * bf2f(B0.z >> 16)    + w1 * bf2f(B1.z >> 16)
                + w2 * bf2f(B2.z >> 16)    + w3 * bf2f(B3.z >> 16);
        acc[6] += w0 * bf2f(B0.w & 0xffff) + w1 * bf2f(B1.w & 0xffff)
                + w2 * bf2f(B2.w & 0xffff) + w3 * bf2f(B3.w & 0xffff);
        acc[7] += w0 * bf2f(B0.w >> 16)    + w1 * bf2f(B1.w >> 16)
                + w2 * bf2f(B2.w >> 16)    + w3 * bf2f(B3.w >> 16);
    }

    // self terms: wave handles nodes m*64 + wave*8 + g (each exactly once)
    {
        const int nl = wave * 8 + g;
        const float dv = dvs[nl];
        const uint4 S = *(const uint4*)&hb[(size_t)(m * 64 + nl) * DIM + q * 8];
        acc[0] += dv * bf2f(S.x & 0xffff);
        acc[1] += dv * bf2f(S.x >> 16);
        acc[2] += dv * bf2f(S.y & 0xffff);
        acc[3] += dv * bf2f(S.y >> 16);
        acc[4] += dv * bf2f(S.z & 0xffff);
        acc[5] += dv * bf2f(S.z >> 16);
        acc[6] += dv * bf2f(S.w & 0xffff);
        acc[7] += dv * bf2f(S.w >> 16);
    }

#pragma unroll
    for (int mm = 8; mm <= 32; mm <<= 1) {
#pragma unroll
        for (int k = 0; k < 8; ++k) acc[k] += __shfl_xor(acc[k], mm, 64);
    }
    if (lane < 8) {
#pragma unroll
        for (int k = 0; k < 8; ++k) wacc[wave][q * 8 + k] = acc[k];
    }
    __syncthreads();
    if (t < DIM) {
        float p = 0.f;
#pragma unroll
        for (int w = 0; w < 8; ++w) p += wacc[w][t];
        pooled[t] = p * (1.0f / DIM);
    }
    __syncthreads();
    if (t < DIM) {
        float o = b2[t];
#pragma unroll
        for (int k = 0; k < DIM; ++k) o += pooled[k] * Ws[k * DIM + t];
        out[(size_t)t * M_POOL + m] = o;
    }
}

// ---------------- launcher --------------------------------------------------

extern "C" void kernel_launch(void* const* d_in, const int* in_sizes, int n_in,
                              void* d_out, int out_size, void* d_ws, size_t ws_size,
                              hipStream_t stream) {
    const float* x  = (const float*)d_in[0];
    const int*   ei = (const int*)d_in[1];   // [2][E]
    const float* ew = (const float*)d_in[2];
    const float* W1 = (const float*)d_in[3];
    const float* b1 = (const float*)d_in[4];
    const float* W2 = (const float*)d_in[5];
    const float* b2 = (const float*)d_in[6];
    float* out = (float*)d_out;

    char* w = (char*)d_ws;
    int*   cursor = (int*)w;   w += (size_t)NCOARSE * CURPAD * 4;    // 16 KB padded
    int*   rowptr = (int*)w;   w += (size_t)(N_NODES + 16) * 4;      // 0.25 MB
    float* dinv   = (float*)w; w += (size_t)N_NODES * 4;             // 0.25 MB
    int2*  csrt   = (int2*)w;  w += (size_t)NCOARSE * SEGCAP * 8;    // 10.5 MB
    u32*   csr    = (u32*)w;   w += (size_t)N_EDGES * 4;             // 4 MB
    u16*   hbf    = (u16*)w;   w += (size_t)N_NODES * DIM * 2;       // 8 MB
    u16*   h1bf   = (u16*)w;                                         // 8 MB

    const int* row = ei;             // edge_index[0]
    const int* col = ei + N_EDGES;   // edge_index[1]

    // build: gemm || coarse-multisplit in one grid, then fine sort (+scan inlined)
    zero_cursor<<<1, 256, 0, stream>>>(cursor);
    fused_gemm_p3<<<FUSED_BLOCKS, 256, 0, stream>>>(x, W1, hbf, col, row, ew,
                                                    cursor, csrt);
    p4_fine<<<NCOARSE, 512, 0, stream>>>(cursor, csrt, csr, rowptr, dinv, hbf);

    // layer 1 aggregate: h1p = bf16(dv * (A h + b1))   (premultiplied)
    aggregate_l1<<<N_NODES / 4, 256, 0, stream>>>(rowptr, csr, hbf, dinv, b1, h1bf);

    // layer 2 + pool + W2-GEMM fused per window (flat contiguous edge range)
    agg2_pool_gemm<<<M_POOL, 512, 0, stream>>>(rowptr, csr, h1bf, dinv, W2, b2, out);
}